// Round 13
// baseline (917.630 us; speedup 1.0000x reference)
//
#include <hip/hip_runtime.h>

#define DD 64
#define GG 64
#define EPSV 1e-5f
#define SLOPE 0.01f

#define AG_WAVES 8
#define AG_NPW 8
#define AG_NODES (AG_WAVES*AG_NPW) // 64 nodes per block (gemm kernel)
#define NRM_NPW 16

// binned CSR build
#define NRANGE 512
#define RSHIFT 8              // 256 nodes per range (512*256 = 131072 >= N)
#define NPR 256
#define ABLK 512              // edge-chunk blocks in phases A1/A3

typedef unsigned short ushort_t;
typedef unsigned int uint_t;
typedef float v2f __attribute__((ext_vector_type(2)));
typedef uint_t v2u __attribute__((ext_vector_type(2)));   // NT-compatible 8-byte vector

__device__ __forceinline__ ushort_t f2bf(float f) {
  uint_t u = __float_as_uint(f);
  uint_t r = (u + 0x7fffu + ((u >> 16) & 1u)) >> 16;   // round-to-nearest-even
  return (ushort_t)r;
}
__device__ __forceinline__ float bf2f(ushort_t s) { return __uint_as_float(((uint_t)s) << 16); }
__device__ __forceinline__ v2f unpk(uint_t u) {      // {lo,hi} bf16 pair -> 2 floats
  v2f r;
  r.x = __uint_as_float(u << 16);
  r.y = __uint_as_float(u & 0xffff0000u);
  return r;
}

// ---------- A1: per-(block,range) histograms, both directions, LDS-only atomics ----------
__global__ __launch_bounds__(256) void bin_count_kernel(const int* __restrict__ src,
                                                        const int* __restrict__ dst,
                                                        int* __restrict__ hist, int E) {
  __shared__ int cf[NRANGE], cb[NRANGE];
  for (int i=threadIdx.x; i<NRANGE; i+=256) { cf[i]=0; cb[i]=0; }
  __syncthreads();
  int epb = (E + ABLK-1)/ABLK;
  int lo = blockIdx.x*epb, hi = lo+epb; if (hi>E) hi=E;
  for (int e=lo+threadIdx.x; e<hi; e+=256) {
    int d = __builtin_nontemporal_load(&dst[e]);
    int s = __builtin_nontemporal_load(&src[e]);
    atomicAdd(&cf[d>>RSHIFT], 1);
    atomicAdd(&cb[s>>RSHIFT], 1);
  }
  __syncthreads();
  for (int r=threadIdx.x; r<NRANGE; r+=256) {
    hist[(size_t)r*ABLK + blockIdx.x]            = cf[r];
    hist[(size_t)(NRANGE+r)*ABLK + blockIdx.x]   = cb[r];
  }
}

// ---------- generic 2-level scan over hist (M = 2*NRANGE*ABLK = 524288) ----------
__global__ void block_sum_kernel(const int* __restrict__ v, int* __restrict__ partial, int M) {
  __shared__ int sm[1024];
  int i = blockIdx.x*1024 + threadIdx.x;
  sm[threadIdx.x] = (i<M) ? v[i] : 0;
  __syncthreads();
  for (int s=512; s>0; s>>=1) {
    if (threadIdx.x < s) sm[threadIdx.x] += sm[threadIdx.x+s];
    __syncthreads();
  }
  if (threadIdx.x==0) partial[blockIdx.x] = sm[0];
}

__global__ void scan_partial_kernel(int* __restrict__ partial, int nb) {  // 512 threads
  __shared__ int sm[512];
  int t = threadIdx.x;
  int v = (t<nb) ? partial[t] : 0;
  int orig = v;
  sm[t] = v; __syncthreads();
  for (int off=1; off<512; off<<=1) {
    int a = (t>=off) ? sm[t-off] : 0;
    __syncthreads();
    v += a; sm[t] = v;
    __syncthreads();
  }
  if (t<nb) partial[t] = v - orig;   // exclusive block offsets
}

__global__ void scan_apply_kernel(const int* __restrict__ v, const int* __restrict__ partial,
                                  int* __restrict__ out, int M) {
  __shared__ int sm[1024];
  int i = blockIdx.x*1024 + threadIdx.x;
  int x = (i<M) ? v[i] : 0;
  int orig = x;
  sm[threadIdx.x] = x; __syncthreads();
  for (int off=1; off<1024; off<<=1) {
    int a = (threadIdx.x>=off) ? sm[threadIdx.x-off] : 0;
    __syncthreads();
    x += a; sm[threadIdx.x] = x;
    __syncthreads();
  }
  if (i<M) out[i] = x - orig + partial[blockIdx.x];   // exclusive scan
}

// ---------- A3: scatter (key,val) records into reserved segments, LDS-only atomics ----------
__global__ __launch_bounds__(256) void bin_scatter_kernel(const int* __restrict__ src,
                                                          const int* __restrict__ dst,
                                                          const int* __restrict__ offs,
                                                          int2* __restrict__ staged, int E) {
  __shared__ int ofF[NRANGE], ofB[NRANGE];
  for (int r=threadIdx.x; r<NRANGE; r+=256) {
    ofF[r] = offs[(size_t)r*ABLK + blockIdx.x];
    ofB[r] = offs[(size_t)(NRANGE+r)*ABLK + blockIdx.x];
  }
  __syncthreads();
  int epb = (E + ABLK-1)/ABLK;
  int lo = blockIdx.x*epb, hi = lo+epb; if (hi>E) hi=E;
  for (int e=lo+threadIdx.x; e<hi; e+=256) {
    int d = __builtin_nontemporal_load(&dst[e]);
    int s = __builtin_nontemporal_load(&src[e]);
    int pf = atomicAdd(&ofF[d>>RSHIFT], 1);
    staged[pf] = make_int2(d, s);              // fwd record: key=dst, val=src
    int pb = atomicAdd(&ofB[s>>RSHIFT], 1);
    staged[pb] = make_int2(s, d);              // bwd record: key=src, val=dst
  }
}

// ---------- B: per-range counting sort -> rp (coalesced) + col (L2-window scatter) ----------
__global__ __launch_bounds__(256) void range_fill_kernel(const int2* __restrict__ staged,
                                                         const int* __restrict__ offs,
                                                         int* __restrict__ rp_f, int* __restrict__ rp_b,
                                                         int* __restrict__ col_f, int* __restrict__ col_b,
                                                         int N, int E) {
  __shared__ int cnt[NPR], noff[NPR], sc[NPR];
  int lr = blockIdx.x;
  int d = lr >> 9, r = lr & (NRANGE-1);
  int start = offs[(size_t)lr*ABLK];
  int end   = (lr+1 < 2*NRANGE) ? offs[(size_t)(lr+1)*ABLK] : 2*E;
  int t = threadIdx.x;
  cnt[t] = 0; __syncthreads();
  for (int k=start+t; k<end; k+=256) {
    int key = staged[k].x;
    atomicAdd(&cnt[key & (NPR-1)], 1);
  }
  __syncthreads();
  int x = cnt[t]; sc[t] = x; __syncthreads();
  for (int off=1; off<NPR; off<<=1) {
    int a = (t>=off) ? sc[t-off] : 0;
    __syncthreads();
    x += a; sc[t] = x;
    __syncthreads();
  }
  noff[t] = x - cnt[t];
  __syncthreads();
  int base = d ? (start - E) : start;
  int node = (r << RSHIFT) + t;
  int* rp = d ? rp_b : rp_f;
  if (node < N)       rp[node] = base + noff[t];
  else if (node == N) rp[N]    = base + noff[t];
  cnt[t] = 0; __syncthreads();
  int* col = d ? col_b : col_f;
  for (int k=start+t; k<end; k+=256) {
    int2 rec = staged[k];
    int li = rec.x & (NPR-1);
    int rank = atomicAdd(&cnt[li], 1);
    col[base + noff[li] + rank] = rec.y;
  }
}

__global__ void cnt_kernel(const int* __restrict__ batch, int* __restrict__ cnt, int N) {
  __shared__ int hist[GG];
  if (threadIdx.x < GG) hist[threadIdx.x] = 0;
  __syncthreads();
  int i = blockIdx.x*blockDim.x + threadIdx.x;
  int stride = gridDim.x*blockDim.x;
  for (int n=i; n<N; n+=stride) atomicAdd(&hist[batch[n]], 1);
  __syncthreads();
  if (threadIdx.x < GG) atomicAdd(&cnt[threadIdx.x], hist[threadIdx.x]);
}

// ----------------- fp32 -> bf16 shadow -----------------
__global__ void tobf16_kernel(const float* __restrict__ in, ushort_t* __restrict__ out, int M) {
  int i = blockIdx.x*blockDim.x + threadIdx.x;
  int stride = gridDim.x*blockDim.x;
  for (int k=i; k<M; k+=stride) out[k] = f2bf(__builtin_nontemporal_load(&in[k]));
}

// ----------------- gather: one wave per node; NT on col/sbuf so hb owns L2 --------------
__global__ __launch_bounds__(256) void gather_kernel(
    const ushort_t* __restrict__ hb,
    const int* __restrict__ rp_f, const int* __restrict__ col_f,
    const int* __restrict__ rp_b, const int* __restrict__ col_b,
    ushort_t* __restrict__ sbufb, int N)
{
  int w = (blockIdx.x*(blockDim.x>>6)) + (threadIdx.x>>6);   // node = global wave id
  if (w >= N) return;
  int lane = threadIdx.x & 63;
  int qt = lane >> 4;        // quarter 0..3
  int g  = lane & 15;        // feature quad: features 4g..4g+3
  const char* hbb = (const char*)hb;
  uint_t goff = (uint_t)g << 3;     // byte offset of this lane's quad within a row

  v2f a01={0.f,0.f}, a23={0.f,0.f}, c01={0.f,0.f}, c23={0.f,0.f};
  int degf, degb;

  {
    int s0 = rp_f[w], e0 = rp_f[w+1];
    degf = e0 - s0;
    for (int base=s0; base<e0; base+=64) {
      int m = e0-base; if (m>64) m=64;
      int jv = (lane<m) ? __builtin_nontemporal_load(&col_f[base+lane]) : 0;
      int q=0;
      for (; 4*q+16 <= m; q+=4) {
        int j0=__shfl(jv,4*q+qt),    j1=__shfl(jv,4*q+4+qt);
        int j2=__shfl(jv,4*q+8+qt),  j3=__shfl(jv,4*q+12+qt);
        uint2 v0 = *(const uint2*)(hbb + ((((uint_t)j0)<<7) | goff));
        uint2 v1 = *(const uint2*)(hbb + ((((uint_t)j1)<<7) | goff));
        uint2 v2 = *(const uint2*)(hbb + ((((uint_t)j2)<<7) | goff));
        uint2 v3 = *(const uint2*)(hbb + ((((uint_t)j3)<<7) | goff));
        a01 += unpk(v0.x); a23 += unpk(v0.y);
        a01 += unpk(v1.x); a23 += unpk(v1.y);
        a01 += unpk(v2.x); a23 += unpk(v2.y);
        a01 += unpk(v3.x); a23 += unpk(v3.y);
      }
      for (; 4*q+qt < m; ++q) {
        int j=__shfl(jv,4*q+qt);
        uint2 v = *(const uint2*)(hbb + ((((uint_t)j)<<7) | goff));
        a01 += unpk(v.x); a23 += unpk(v.y);
      }
    }
  }
  {
    int s1 = rp_b[w], e1 = rp_b[w+1];
    degb = e1 - s1;
    for (int base=s1; base<e1; base+=64) {
      int m = e1-base; if (m>64) m=64;
      int jv = (lane<m) ? __builtin_nontemporal_load(&col_b[base+lane]) : 0;
      int q=0;
      for (; 4*q+16 <= m; q+=4) {
        int j0=__shfl(jv,4*q+qt),    j1=__shfl(jv,4*q+4+qt);
        int j2=__shfl(jv,4*q+8+qt),  j3=__shfl(jv,4*q+12+qt);
        uint2 v0 = *(const uint2*)(hbb + ((((uint_t)j0)<<7) | goff));
        uint2 v1 = *(const uint2*)(hbb + ((((uint_t)j1)<<7) | goff));
        uint2 v2 = *(const uint2*)(hbb + ((((uint_t)j2)<<7) | goff));
        uint2 v3 = *(const uint2*)(hbb + ((((uint_t)j3)<<7) | goff));
        c01 += unpk(v0.x); c23 += unpk(v0.y);
        c01 += unpk(v1.x); c23 += unpk(v1.y);
        c01 += unpk(v2.x); c23 += unpk(v2.y);
        c01 += unpk(v3.x); c23 += unpk(v3.y);
      }
      for (; 4*q+qt < m; ++q) {
        int j=__shfl(jv,4*q+qt);
        uint2 v = *(const uint2*)(hbb + ((((uint_t)j)<<7) | goff));
        c01 += unpk(v.x); c23 += unpk(v.y);
      }
    }
  }

  float df = fmaxf((float)degf, 1.f);
  float db = fmaxf((float)degb, 1.f);
  float s0v = 0.5f*(a01.x/df + c01.x/db);
  float s1v = 0.5f*(a01.y/df + c01.y/db);
  float s2v = 0.5f*(a23.x/df + c23.x/db);
  float s3v = 0.5f*(a23.y/df + c23.y/db);
  s0v += __shfl_xor(s0v,16); s0v += __shfl_xor(s0v,32);
  s1v += __shfl_xor(s1v,16); s1v += __shfl_xor(s1v,32);
  s2v += __shfl_xor(s2v,16); s2v += __shfl_xor(s2v,32);
  s3v += __shfl_xor(s3v,16); s3v += __shfl_xor(s3v,32);
  if (qt==0) {
    v2u pk;
    pk.x = (uint_t)f2bf(s0v) | ((uint_t)f2bf(s1v) << 16);
    pk.y = (uint_t)f2bf(s2v) | ((uint_t)f2bf(s3v) << 16);
    __builtin_nontemporal_store(pk, (v2u*)&((uint_t*)sbufb)[(size_t)w*32 + 2*g]);
  }
}

// --------- dual GEMM + graph sum & sum-of-squares (vectorized bf16 staging) ---------
__global__ __launch_bounds__(512) void gemm_kernel(
    const ushort_t* __restrict__ hb, const ushort_t* __restrict__ sbufb,
    const float* __restrict__ Wl, const float* __restrict__ Wr, const float* __restrict__ bias,
    const int* __restrict__ batch,
    ushort_t* __restrict__ tb, float* __restrict__ gsum, float* __restrict__ gsq, int N)
{
  __shared__ float srow[AG_NODES][DD];
  __shared__ float hrow[AG_NODES][DD];

  int wid = threadIdx.x >> 6;
  int lane = threadIdx.x & 63;
  int sub = lane >> 4;       // node within 4-group
  int g   = lane & 15;       // feature quad
  int nodeBase = blockIdx.x*AG_NODES + wid*AG_NPW;

  #pragma unroll
  for (int nn=0; nn<AG_NPW; nn+=4) {
    int node = nodeBase + nn + sub;
    v2u sv = {0,0};
    uint2 hv = make_uint2(0,0);
    if (node < N) {
      sv = __builtin_nontemporal_load((const v2u*)&((const uint_t*)sbufb)[(size_t)node*32 + 2*g]);
      hv = ((const uint2*)hb)[(size_t)node*16 + g];    // cacheable: next gather reuses
    }
    v2f s01 = unpk(sv.x), s23 = unpk(sv.y);
    v2f h01 = unpk(hv.x), h23 = unpk(hv.y);
    *(float4*)&srow[wid*AG_NPW+nn+sub][4*g] = make_float4(s01.x,s01.y,s23.x,s23.y);
    *(float4*)&hrow[wid*AG_NPW+nn+sub][4*g] = make_float4(h01.x,h01.y,h23.x,h23.y);
  }
  // no barrier: each wave wrote and reads only its own 8 rows

  float bv = bias[lane];
  float tacc[AG_NPW];
  #pragma unroll
  for (int nn=0; nn<AG_NPW; ++nn) tacc[nn]=bv;

  for (int k=0; k<DD; k+=4) {
    float w0 = Wl[(k+0)*DD+lane], w1 = Wl[(k+1)*DD+lane];
    float w2 = Wl[(k+2)*DD+lane], w3 = Wl[(k+3)*DD+lane];
    float r0 = Wr[(k+0)*DD+lane], r1 = Wr[(k+1)*DD+lane];
    float r2 = Wr[(k+2)*DD+lane], r3 = Wr[(k+3)*DD+lane];
    #pragma unroll
    for (int nn=0; nn<AG_NPW; ++nn) {
      float4 sv = *(const float4*)&srow[wid*AG_NPW+nn][k];
      float4 hv = *(const float4*)&hrow[wid*AG_NPW+nn][k];
      tacc[nn] += sv.x*w0 + sv.y*w1 + sv.z*w2 + sv.w*w3
                + hv.x*r0 + hv.y*r1 + hv.z*r2 + hv.w*r3;
    }
  }

  int gcur = -1; float gacc = 0.f, qacc = 0.f;
  for (int nn=0; nn<AG_NPW; ++nn) {
    int node = nodeBase+nn;
    if (node >= N) break;
    __builtin_nontemporal_store(f2bf(tacc[nn]), &tb[(size_t)node*DD+lane]);
    int g2 = batch[node];
    if (g2 != gcur) {
      if (gcur >= 0) {
        atomicAdd(&gsum[gcur*DD+lane], gacc);
        atomicAdd(&gsq[gcur*DD+lane], qacc);
      }
      gcur = g2; gacc = 0.f; qacc = 0.f;
    }
    gacc += tacc[nn];
    qacc += tacc[nn]*tacc[nn];
  }
  if (gcur >= 0) {
    atomicAdd(&gsum[gcur*DD+lane], gacc);
    atomicAdd(&gsq[gcur*DD+lane], qacc);
  }
}

// ---- GraphNorm (var from sums) + leaky + residual, bf16 state in-place; last fuses pool ----
__global__ void norm2_kernel(const ushort_t* __restrict__ tb,
                             const float* __restrict__ gsum, const float* __restrict__ gsq,
                             const int* __restrict__ cnt, const int* __restrict__ batch,
                             const float* __restrict__ gw, const float* __restrict__ gb,
                             const float* __restrict__ gms,
                             ushort_t* __restrict__ hb,
                             float* __restrict__ pout,
                             int resid, int last, int N)
{
  int wid = (blockIdx.x*blockDim.x + threadIdx.x) >> 6;
  int lane = threadIdx.x & 63;
  int base = wid*NRM_NPW;
  if (base >= N) return;
  float wv = gw[lane], bv = gb[lane], msv = gms[lane];
  float cms = msv*(2.f - msv);
  int gcur=-1; float rs=0.f, mean=0.f, pacc=0.f;
  int end = base+NRM_NPW; if (end>N) end=N;
  for (int node=base; node<end; ++node) {
    int g = batch[node];
    if (g!=gcur) {
      if (last && gcur>=0) atomicAdd(&pout[gcur*DD+lane], pacc);
      pacc = 0.f;
      float invc = 1.f/fmaxf((float)cnt[g],1.f);
      mean = gsum[g*DD+lane]*invc;
      float msq = gsq[g*DD+lane]*invc;
      float var = msq - cms*mean*mean;         // E[(t-ms*mean)^2]
      rs = rsqrtf(var + EPSV);
      gcur=g;
    }
    float u = bf2f(__builtin_nontemporal_load(&tb[(size_t)node*DD+lane])) - msv*mean;
    float y = wv*u*rs + bv;
    y = (y>=0.f) ? y : SLOPE*y;
    float hv = resid ? (bf2f(hb[(size_t)node*DD+lane]) + y) : y;
    if (last) {
      pacc += hv;                  // final h never re-read: pool only
    } else {
      hb[(size_t)node*DD+lane] = f2bf(hv);   // in-place: all layer-i readers done
    }
  }
  if (last && gcur>=0) atomicAdd(&pout[gcur*DD+lane], pacc);
}

__global__ void finalize_kernel(const float* __restrict__ pout, const int* __restrict__ cnt,
                                float* __restrict__ out)
{
  int i = blockIdx.x*blockDim.x + threadIdx.x;
  if (i < GG*DD) {
    float invc = 1.f/fmaxf((float)cnt[i>>6],1.f);
    out[i] = pout[i]*invc;
  }
}

extern "C" void kernel_launch(void* const* d_in, const int* in_sizes, int n_in,
                              void* d_out, int out_size, void* d_ws, size_t ws_size,
                              hipStream_t stream)
{
  const float* x    = (const float*)d_in[0];
  const int*  ei    = (const int*)d_in[1];
  const int*  batch = (const int*)d_in[2];
  const float* W_l  = (const float*)d_in[3];
  const float* W_r  = (const float*)d_in[4];
  const float* bias = (const float*)d_in[5];
  const float* gn_w = (const float*)d_in[6];
  const float* gn_b = (const float*)d_in[7];
  const float* gn_ms= (const float*)d_in[8];

  int N = in_sizes[2];
  int E = in_sizes[1]/2;
  int L = in_sizes[5]/DD;
  const int* src = ei;
  const int* dst = ei + E;

  // ---- workspace layout: zero-zone first (single memset) ----
  char* p = (char*)d_ws;
  int*   cnt   = (int*)p;   p += GG*4;
  float* gsum  = (float*)p; p += (size_t)L*GG*DD*4;
  float* gsq   = (float*)p; p += (size_t)L*GG*DD*4;
  float* pout  = (float*)p; p += GG*DD*4;
  size_t zeroBytes = (char*)p - (char*)d_ws;

  int2* staged = (int2*)p; p += (size_t)2*E*8;            // CSR build records (25.6MB)
  ushort_t* tb    = (ushort_t*)p; p += (size_t)N*DD*2;
  ushort_t* sbufb = (ushort_t*)p; p += (size_t)N*DD*2;
  ushort_t* hb    = (ushort_t*)p; p += (size_t)N*DD*2;
  int* rp_f    = (int*)p; p += (size_t)(N+1)*4;
  int* rp_b    = (int*)p; p += (size_t)(N+1)*4;
  int* col_f   = (int*)p; p += (size_t)E*4;
  int* col_b   = (int*)p; p += (size_t)E*4;
  int* hist    = (int*)p; p += (size_t)2*NRANGE*ABLK*4;   // 2MB
  int* offs    = (int*)p; p += (size_t)2*NRANGE*ABLK*4;   // 2MB
  int* partial = (int*)p; p += 512*4;

  hipMemsetAsync(d_ws, 0, zeroBytes, stream);

  const int M = 2*NRANGE*ABLK;  // 524288
  bin_count_kernel<<<ABLK, 256, 0, stream>>>(src, dst, hist, E);
  block_sum_kernel<<<(M+1023)/1024, 1024, 0, stream>>>(hist, partial, M);
  scan_partial_kernel<<<1, 512, 0, stream>>>(partial, (M+1023)/1024);
  scan_apply_kernel<<<(M+1023)/1024, 1024, 0, stream>>>(hist, partial, offs, M);
  bin_scatter_kernel<<<ABLK, 256, 0, stream>>>(src, dst, offs, staged, E);
  range_fill_kernel<<<2*NRANGE, 256, 0, stream>>>(staged, offs, rp_f, rp_b, col_f, col_b, N, E);

  cnt_kernel<<<391, 256, 0, stream>>>(batch, cnt, N);
  tobf16_kernel<<<2048, 256, 0, stream>>>(x, hb, N*DD);

  int gthBlocks = (N + 3)/4;           // 4 waves (nodes) per 256-thread block
  int agBlocks = (N + AG_NODES-1)/AG_NODES;
  int nrmWaves = (N + NRM_NPW-1)/NRM_NPW;
  int nrmBlocks = (nrmWaves+3)/4;

  for (int i=0; i<L; ++i) {
    float* gsum_i = gsum + (size_t)i*GG*DD;
    float* gsq_i  = gsq  + (size_t)i*GG*DD;
    int last = (i==L-1) ? 1 : 0;
    gather_kernel<<<gthBlocks, 256, 0, stream>>>(hb, rp_f, col_f, rp_b, col_b, sbufb, N);
    gemm_kernel<<<agBlocks, 512, 0, stream>>>(hb, sbufb,
                                              W_l+(size_t)i*DD*DD, W_r+(size_t)i*DD*DD,
                                              bias+(size_t)i*DD, batch, tb, gsum_i, gsq_i, N);
    norm2_kernel<<<nrmBlocks, 256, 0, stream>>>(tb, gsum_i, gsq_i, cnt, batch,
                                                gn_w+(size_t)i*DD, gn_b+(size_t)i*DD,
                                                gn_ms+(size_t)i*DD,
                                                hb, pout, (i>=2)?1:0, last, N);
  }
  finalize_kernel<<<16, 256, 0, stream>>>(pout, cnt, (float*)d_out);
}

// Round 14
// 835.154 us; speedup vs baseline: 1.0988x; 1.0988x over previous
//
#include <hip/hip_runtime.h>

#define DD 64
#define GG 64
#define EPSV 1e-5f
#define SLOPE 0.01f

#define AG_WAVES 8
#define AG_NPW 8
#define AG_NODES (AG_WAVES*AG_NPW) // 64 nodes per block (gemm kernel)
#define NRM_NPW 16

// binned CSR build
#define NRANGE 512
#define RSHIFT 8              // 256 nodes per range (512*256 = 131072 >= N)
#define NPR 256
#define ABLK 512              // edge-chunk blocks in phases A1/A3

typedef unsigned short ushort_t;
typedef unsigned int uint_t;
typedef float v2f __attribute__((ext_vector_type(2)));

__device__ __forceinline__ ushort_t f2bf(float f) {
  uint_t u = __float_as_uint(f);
  uint_t r = (u + 0x7fffu + ((u >> 16) & 1u)) >> 16;   // round-to-nearest-even
  return (ushort_t)r;
}
__device__ __forceinline__ float bf2f(ushort_t s) { return __uint_as_float(((uint_t)s) << 16); }
__device__ __forceinline__ v2f unpk(uint_t u) {      // {lo,hi} bf16 pair -> 2 floats
  v2f r;
  r.x = __uint_as_float(u << 16);
  r.y = __uint_as_float(u & 0xffff0000u);
  return r;
}

// ---------- A1: per-(block,range) histograms, both directions, LDS-only atomics ----------
__global__ __launch_bounds__(256) void bin_count_kernel(const int* __restrict__ src,
                                                        const int* __restrict__ dst,
                                                        int* __restrict__ hist, int E) {
  __shared__ int cf[NRANGE], cb[NRANGE];
  for (int i=threadIdx.x; i<NRANGE; i+=256) { cf[i]=0; cb[i]=0; }
  __syncthreads();
  int epb = (E + ABLK-1)/ABLK;
  int lo = blockIdx.x*epb, hi = lo+epb; if (hi>E) hi=E;
  for (int e=lo+threadIdx.x; e<hi; e+=256) {
    int d = __builtin_nontemporal_load(&dst[e]);
    int s = __builtin_nontemporal_load(&src[e]);
    atomicAdd(&cf[d>>RSHIFT], 1);
    atomicAdd(&cb[s>>RSHIFT], 1);
  }
  __syncthreads();
  for (int r=threadIdx.x; r<NRANGE; r+=256) {
    hist[(size_t)r*ABLK + blockIdx.x]            = cf[r];
    hist[(size_t)(NRANGE+r)*ABLK + blockIdx.x]   = cb[r];
  }
}

// ---------- generic 2-level scan over hist (M = 2*NRANGE*ABLK = 524288) ----------
__global__ void block_sum_kernel(const int* __restrict__ v, int* __restrict__ partial, int M) {
  __shared__ int sm[1024];
  int i = blockIdx.x*1024 + threadIdx.x;
  sm[threadIdx.x] = (i<M) ? v[i] : 0;
  __syncthreads();
  for (int s=512; s>0; s>>=1) {
    if (threadIdx.x < s) sm[threadIdx.x] += sm[threadIdx.x+s];
    __syncthreads();
  }
  if (threadIdx.x==0) partial[blockIdx.x] = sm[0];
}

__global__ void scan_partial_kernel(int* __restrict__ partial, int nb) {  // 512 threads
  __shared__ int sm[512];
  int t = threadIdx.x;
  int v = (t<nb) ? partial[t] : 0;
  int orig = v;
  sm[t] = v; __syncthreads();
  for (int off=1; off<512; off<<=1) {
    int a = (t>=off) ? sm[t-off] : 0;
    __syncthreads();
    v += a; sm[t] = v;
    __syncthreads();
  }
  if (t<nb) partial[t] = v - orig;   // exclusive block offsets
}

__global__ void scan_apply_kernel(const int* __restrict__ v, const int* __restrict__ partial,
                                  int* __restrict__ out, int M) {
  __shared__ int sm[1024];
  int i = blockIdx.x*1024 + threadIdx.x;
  int x = (i<M) ? v[i] : 0;
  int orig = x;
  sm[threadIdx.x] = x; __syncthreads();
  for (int off=1; off<1024; off<<=1) {
    int a = (threadIdx.x>=off) ? sm[threadIdx.x-off] : 0;
    __syncthreads();
    x += a; sm[threadIdx.x] = x;
    __syncthreads();
  }
  if (i<M) out[i] = x - orig + partial[blockIdx.x];   // exclusive scan
}

// ---------- A3: scatter (key,val) records into reserved segments, LDS-only atomics ----------
__global__ __launch_bounds__(256) void bin_scatter_kernel(const int* __restrict__ src,
                                                          const int* __restrict__ dst,
                                                          const int* __restrict__ offs,
                                                          int2* __restrict__ staged, int E) {
  __shared__ int ofF[NRANGE], ofB[NRANGE];
  for (int r=threadIdx.x; r<NRANGE; r+=256) {
    ofF[r] = offs[(size_t)r*ABLK + blockIdx.x];
    ofB[r] = offs[(size_t)(NRANGE+r)*ABLK + blockIdx.x];
  }
  __syncthreads();
  int epb = (E + ABLK-1)/ABLK;
  int lo = blockIdx.x*epb, hi = lo+epb; if (hi>E) hi=E;
  for (int e=lo+threadIdx.x; e<hi; e+=256) {
    int d = __builtin_nontemporal_load(&dst[e]);
    int s = __builtin_nontemporal_load(&src[e]);
    int pf = atomicAdd(&ofF[d>>RSHIFT], 1);
    staged[pf] = make_int2(d, s);              // fwd record: key=dst, val=src
    int pb = atomicAdd(&ofB[s>>RSHIFT], 1);
    staged[pb] = make_int2(s, d);              // bwd record: key=src, val=dst
  }
}

// ---------- B: per-range counting sort -> rp (coalesced) + col (L2-window scatter) ----------
__global__ __launch_bounds__(256) void range_fill_kernel(const int2* __restrict__ staged,
                                                         const int* __restrict__ offs,
                                                         int* __restrict__ rp_f, int* __restrict__ rp_b,
                                                         int* __restrict__ col_f, int* __restrict__ col_b,
                                                         int N, int E) {
  __shared__ int cnt[NPR], noff[NPR], sc[NPR];
  int lr = blockIdx.x;
  int d = lr >> 9, r = lr & (NRANGE-1);
  int start = offs[(size_t)lr*ABLK];
  int end   = (lr+1 < 2*NRANGE) ? offs[(size_t)(lr+1)*ABLK] : 2*E;
  int t = threadIdx.x;
  cnt[t] = 0; __syncthreads();
  for (int k=start+t; k<end; k+=256) {
    int key = staged[k].x;
    atomicAdd(&cnt[key & (NPR-1)], 1);
  }
  __syncthreads();
  int x = cnt[t]; sc[t] = x; __syncthreads();
  for (int off=1; off<NPR; off<<=1) {
    int a = (t>=off) ? sc[t-off] : 0;
    __syncthreads();
    x += a; sc[t] = x;
    __syncthreads();
  }
  noff[t] = x - cnt[t];
  __syncthreads();
  int base = d ? (start - E) : start;
  int node = (r << RSHIFT) + t;
  int* rp = d ? rp_b : rp_f;
  if (node < N)       rp[node] = base + noff[t];
  else if (node == N) rp[N]    = base + noff[t];
  cnt[t] = 0; __syncthreads();
  int* col = d ? col_b : col_f;
  for (int k=start+t; k<end; k+=256) {
    int2 rec = staged[k];
    int li = rec.x & (NPR-1);
    int rank = atomicAdd(&cnt[li], 1);
    col[base + noff[li] + rank] = rec.y;
  }
}

__global__ void cnt_kernel(const int* __restrict__ batch, int* __restrict__ cnt, int N) {
  __shared__ int hist[GG];
  if (threadIdx.x < GG) hist[threadIdx.x] = 0;
  __syncthreads();
  int i = blockIdx.x*blockDim.x + threadIdx.x;
  int stride = gridDim.x*blockDim.x;
  for (int n=i; n<N; n+=stride) atomicAdd(&hist[batch[n]], 1);
  __syncthreads();
  if (threadIdx.x < GG) atomicAdd(&cnt[threadIdx.x], hist[threadIdx.x]);
}

// ----------------- fp32 -> bf16 shadow -----------------
__global__ void tobf16_kernel(const float* __restrict__ in, ushort_t* __restrict__ out, int M) {
  int i = blockIdx.x*blockDim.x + threadIdx.x;
  int stride = gridDim.x*blockDim.x;
  for (int k=i; k<M; k+=stride) out[k] = f2bf(in[k]);
}

// ----------------- gather: one wave per node; 32-bit offsets + packed accumulate --------
// (r11 configuration: all loads/stores cached — NT variants regressed in r13)
__global__ __launch_bounds__(256) void gather_kernel(
    const ushort_t* __restrict__ hb,
    const int* __restrict__ rp_f, const int* __restrict__ col_f,
    const int* __restrict__ rp_b, const int* __restrict__ col_b,
    ushort_t* __restrict__ sbufb, int N)
{
  int w = (blockIdx.x*(blockDim.x>>6)) + (threadIdx.x>>6);   // node = global wave id
  if (w >= N) return;
  int lane = threadIdx.x & 63;
  int qt = lane >> 4;        // quarter 0..3
  int g  = lane & 15;        // feature quad: features 4g..4g+3
  const char* hbb = (const char*)hb;
  uint_t goff = (uint_t)g << 3;     // byte offset of this lane's quad within a row

  v2f a01={0.f,0.f}, a23={0.f,0.f}, c01={0.f,0.f}, c23={0.f,0.f};
  int degf, degb;

  {
    int s0 = rp_f[w], e0 = rp_f[w+1];
    degf = e0 - s0;
    for (int base=s0; base<e0; base+=64) {
      int m = e0-base; if (m>64) m=64;
      int jv = (lane<m) ? col_f[base+lane] : 0;
      int q=0;
      for (; 4*q+16 <= m; q+=4) {
        int j0=__shfl(jv,4*q+qt),    j1=__shfl(jv,4*q+4+qt);
        int j2=__shfl(jv,4*q+8+qt),  j3=__shfl(jv,4*q+12+qt);
        uint2 v0 = *(const uint2*)(hbb + ((((uint_t)j0)<<7) | goff));
        uint2 v1 = *(const uint2*)(hbb + ((((uint_t)j1)<<7) | goff));
        uint2 v2 = *(const uint2*)(hbb + ((((uint_t)j2)<<7) | goff));
        uint2 v3 = *(const uint2*)(hbb + ((((uint_t)j3)<<7) | goff));
        a01 += unpk(v0.x); a23 += unpk(v0.y);
        a01 += unpk(v1.x); a23 += unpk(v1.y);
        a01 += unpk(v2.x); a23 += unpk(v2.y);
        a01 += unpk(v3.x); a23 += unpk(v3.y);
      }
      for (; 4*q+qt < m; ++q) {
        int j=__shfl(jv,4*q+qt);
        uint2 v = *(const uint2*)(hbb + ((((uint_t)j)<<7) | goff));
        a01 += unpk(v.x); a23 += unpk(v.y);
      }
    }
  }
  {
    int s1 = rp_b[w], e1 = rp_b[w+1];
    degb = e1 - s1;
    for (int base=s1; base<e1; base+=64) {
      int m = e1-base; if (m>64) m=64;
      int jv = (lane<m) ? col_b[base+lane] : 0;
      int q=0;
      for (; 4*q+16 <= m; q+=4) {
        int j0=__shfl(jv,4*q+qt),    j1=__shfl(jv,4*q+4+qt);
        int j2=__shfl(jv,4*q+8+qt),  j3=__shfl(jv,4*q+12+qt);
        uint2 v0 = *(const uint2*)(hbb + ((((uint_t)j0)<<7) | goff));
        uint2 v1 = *(const uint2*)(hbb + ((((uint_t)j1)<<7) | goff));
        uint2 v2 = *(const uint2*)(hbb + ((((uint_t)j2)<<7) | goff));
        uint2 v3 = *(const uint2*)(hbb + ((((uint_t)j3)<<7) | goff));
        c01 += unpk(v0.x); c23 += unpk(v0.y);
        c01 += unpk(v1.x); c23 += unpk(v1.y);
        c01 += unpk(v2.x); c23 += unpk(v2.y);
        c01 += unpk(v3.x); c23 += unpk(v3.y);
      }
      for (; 4*q+qt < m; ++q) {
        int j=__shfl(jv,4*q+qt);
        uint2 v = *(const uint2*)(hbb + ((((uint_t)j)<<7) | goff));
        c01 += unpk(v.x); c23 += unpk(v.y);
      }
    }
  }

  float df = fmaxf((float)degf, 1.f);
  float db = fmaxf((float)degb, 1.f);
  float s0v = 0.5f*(a01.x/df + c01.x/db);
  float s1v = 0.5f*(a01.y/df + c01.y/db);
  float s2v = 0.5f*(a23.x/df + c23.x/db);
  float s3v = 0.5f*(a23.y/df + c23.y/db);
  s0v += __shfl_xor(s0v,16); s0v += __shfl_xor(s0v,32);
  s1v += __shfl_xor(s1v,16); s1v += __shfl_xor(s1v,32);
  s2v += __shfl_xor(s2v,16); s2v += __shfl_xor(s2v,32);
  s3v += __shfl_xor(s3v,16); s3v += __shfl_xor(s3v,32);
  if (qt==0) {
    uint_t p0 = (uint_t)f2bf(s0v) | ((uint_t)f2bf(s1v) << 16);
    uint_t p1 = (uint_t)f2bf(s2v) | ((uint_t)f2bf(s3v) << 16);
    *(uint2*)&((uint_t*)sbufb)[(size_t)w*32 + 2*g] = make_uint2(p0, p1);
  }
}

// --------- dual GEMM + graph sum & sum-of-squares (vectorized bf16 staging, cached) ---------
__global__ __launch_bounds__(512) void gemm_kernel(
    const ushort_t* __restrict__ hb, const ushort_t* __restrict__ sbufb,
    const float* __restrict__ Wl, const float* __restrict__ Wr, const float* __restrict__ bias,
    const int* __restrict__ batch,
    ushort_t* __restrict__ tb, float* __restrict__ gsum, float* __restrict__ gsq, int N)
{
  __shared__ float srow[AG_NODES][DD];
  __shared__ float hrow[AG_NODES][DD];

  int wid = threadIdx.x >> 6;
  int lane = threadIdx.x & 63;
  int sub = lane >> 4;       // node within 4-group
  int g   = lane & 15;       // feature quad
  int nodeBase = blockIdx.x*AG_NODES + wid*AG_NPW;

  #pragma unroll
  for (int nn=0; nn<AG_NPW; nn+=4) {
    int node = nodeBase + nn + sub;
    uint2 sv = make_uint2(0,0), hv = make_uint2(0,0);
    if (node < N) {
      sv = ((const uint2*)sbufb)[(size_t)node*16 + g];
      hv = ((const uint2*)hb)[(size_t)node*16 + g];
    }
    v2f s01 = unpk(sv.x), s23 = unpk(sv.y);
    v2f h01 = unpk(hv.x), h23 = unpk(hv.y);
    *(float4*)&srow[wid*AG_NPW+nn+sub][4*g] = make_float4(s01.x,s01.y,s23.x,s23.y);
    *(float4*)&hrow[wid*AG_NPW+nn+sub][4*g] = make_float4(h01.x,h01.y,h23.x,h23.y);
  }
  // no barrier: each wave wrote and reads only its own 8 rows

  float bv = bias[lane];
  float tacc[AG_NPW];
  #pragma unroll
  for (int nn=0; nn<AG_NPW; ++nn) tacc[nn]=bv;

  for (int k=0; k<DD; k+=4) {
    float w0 = Wl[(k+0)*DD+lane], w1 = Wl[(k+1)*DD+lane];
    float w2 = Wl[(k+2)*DD+lane], w3 = Wl[(k+3)*DD+lane];
    float r0 = Wr[(k+0)*DD+lane], r1 = Wr[(k+1)*DD+lane];
    float r2 = Wr[(k+2)*DD+lane], r3 = Wr[(k+3)*DD+lane];
    #pragma unroll
    for (int nn=0; nn<AG_NPW; ++nn) {
      float4 sv = *(const float4*)&srow[wid*AG_NPW+nn][k];
      float4 hv = *(const float4*)&hrow[wid*AG_NPW+nn][k];
      tacc[nn] += sv.x*w0 + sv.y*w1 + sv.z*w2 + sv.w*w3
                + hv.x*r0 + hv.y*r1 + hv.z*r2 + hv.w*r3;
    }
  }

  int gcur = -1; float gacc = 0.f, qacc = 0.f;
  for (int nn=0; nn<AG_NPW; ++nn) {
    int node = nodeBase+nn;
    if (node >= N) break;
    tb[(size_t)node*DD+lane] = f2bf(tacc[nn]);
    int g2 = batch[node];
    if (g2 != gcur) {
      if (gcur >= 0) {
        atomicAdd(&gsum[gcur*DD+lane], gacc);
        atomicAdd(&gsq[gcur*DD+lane], qacc);
      }
      gcur = g2; gacc = 0.f; qacc = 0.f;
    }
    gacc += tacc[nn];
    qacc += tacc[nn]*tacc[nn];
  }
  if (gcur >= 0) {
    atomicAdd(&gsum[gcur*DD+lane], gacc);
    atomicAdd(&gsq[gcur*DD+lane], qacc);
  }
}

// ---- GraphNorm (var from sums) + leaky + residual, bf16 state in-place; last fuses pool ----
__global__ void norm2_kernel(const ushort_t* __restrict__ tb,
                             const float* __restrict__ gsum, const float* __restrict__ gsq,
                             const int* __restrict__ cnt, const int* __restrict__ batch,
                             const float* __restrict__ gw, const float* __restrict__ gb,
                             const float* __restrict__ gms,
                             ushort_t* __restrict__ hb,
                             float* __restrict__ pout,
                             int resid, int last, int N)
{
  int wid = (blockIdx.x*blockDim.x + threadIdx.x) >> 6;
  int lane = threadIdx.x & 63;
  int base = wid*NRM_NPW;
  if (base >= N) return;
  float wv = gw[lane], bv = gb[lane], msv = gms[lane];
  float cms = msv*(2.f - msv);
  int gcur=-1; float rs=0.f, mean=0.f, pacc=0.f;
  int end = base+NRM_NPW; if (end>N) end=N;
  for (int node=base; node<end; ++node) {
    int g = batch[node];
    if (g!=gcur) {
      if (last && gcur>=0) atomicAdd(&pout[gcur*DD+lane], pacc);
      pacc = 0.f;
      float invc = 1.f/fmaxf((float)cnt[g],1.f);
      mean = gsum[g*DD+lane]*invc;
      float msq = gsq[g*DD+lane]*invc;
      float var = msq - cms*mean*mean;         // E[(t-ms*mean)^2]
      rs = rsqrtf(var + EPSV);
      gcur=g;
    }
    float u = bf2f(tb[(size_t)node*DD+lane]) - msv*mean;
    float y = wv*u*rs + bv;
    y = (y>=0.f) ? y : SLOPE*y;
    float hv = resid ? (bf2f(hb[(size_t)node*DD+lane]) + y) : y;
    if (last) {
      pacc += hv;                  // final h never re-read: pool only
    } else {
      hb[(size_t)node*DD+lane] = f2bf(hv);   // in-place: all layer-i readers done
    }
  }
  if (last && gcur>=0) atomicAdd(&pout[gcur*DD+lane], pacc);
}

__global__ void finalize_kernel(const float* __restrict__ pout, const int* __restrict__ cnt,
                                float* __restrict__ out)
{
  int i = blockIdx.x*blockDim.x + threadIdx.x;
  if (i < GG*DD) {
    float invc = 1.f/fmaxf((float)cnt[i>>6],1.f);
    out[i] = pout[i]*invc;
  }
}

extern "C" void kernel_launch(void* const* d_in, const int* in_sizes, int n_in,
                              void* d_out, int out_size, void* d_ws, size_t ws_size,
                              hipStream_t stream)
{
  const float* x    = (const float*)d_in[0];
  const int*  ei    = (const int*)d_in[1];
  const int*  batch = (const int*)d_in[2];
  const float* W_l  = (const float*)d_in[3];
  const float* W_r  = (const float*)d_in[4];
  const float* bias = (const float*)d_in[5];
  const float* gn_w = (const float*)d_in[6];
  const float* gn_b = (const float*)d_in[7];
  const float* gn_ms= (const float*)d_in[8];

  int N = in_sizes[2];
  int E = in_sizes[1]/2;
  int L = in_sizes[5]/DD;
  const int* src = ei;
  const int* dst = ei + E;

  // ---- workspace layout: zero-zone first (single memset) ----
  char* p = (char*)d_ws;
  int*   cnt   = (int*)p;   p += GG*4;
  float* gsum  = (float*)p; p += (size_t)L*GG*DD*4;
  float* gsq   = (float*)p; p += (size_t)L*GG*DD*4;
  float* pout  = (float*)p; p += GG*DD*4;
  size_t zeroBytes = (char*)p - (char*)d_ws;

  int2* staged = (int2*)p; p += (size_t)2*E*8;            // CSR build records (25.6MB)
  ushort_t* tb    = (ushort_t*)p; p += (size_t)N*DD*2;
  ushort_t* sbufb = (ushort_t*)p; p += (size_t)N*DD*2;
  ushort_t* hb    = (ushort_t*)p; p += (size_t)N*DD*2;
  int* rp_f    = (int*)p; p += (size_t)(N+1)*4;
  int* rp_b    = (int*)p; p += (size_t)(N+1)*4;
  int* col_f   = (int*)p; p += (size_t)E*4;
  int* col_b   = (int*)p; p += (size_t)E*4;
  int* hist    = (int*)p; p += (size_t)2*NRANGE*ABLK*4;   // 2MB
  int* offs    = (int*)p; p += (size_t)2*NRANGE*ABLK*4;   // 2MB
  int* partial = (int*)p; p += 512*4;

  hipMemsetAsync(d_ws, 0, zeroBytes, stream);

  const int M = 2*NRANGE*ABLK;  // 524288
  bin_count_kernel<<<ABLK, 256, 0, stream>>>(src, dst, hist, E);
  block_sum_kernel<<<(M+1023)/1024, 1024, 0, stream>>>(hist, partial, M);
  scan_partial_kernel<<<1, 512, 0, stream>>>(partial, (M+1023)/1024);
  scan_apply_kernel<<<(M+1023)/1024, 1024, 0, stream>>>(hist, partial, offs, M);
  bin_scatter_kernel<<<ABLK, 256, 0, stream>>>(src, dst, offs, staged, E);
  range_fill_kernel<<<2*NRANGE, 256, 0, stream>>>(staged, offs, rp_f, rp_b, col_f, col_b, N, E);

  cnt_kernel<<<391, 256, 0, stream>>>(batch, cnt, N);
  tobf16_kernel<<<2048, 256, 0, stream>>>(x, hb, N*DD);

  int gthBlocks = (N + 3)/4;           // 4 waves (nodes) per 256-thread block
  int agBlocks = (N + AG_NODES-1)/AG_NODES;
  int nrmWaves = (N + NRM_NPW-1)/NRM_NPW;
  int nrmBlocks = (nrmWaves+3)/4;

  for (int i=0; i<L; ++i) {
    float* gsum_i = gsum + (size_t)i*GG*DD;
    float* gsq_i  = gsq  + (size_t)i*GG*DD;
    int last = (i==L-1) ? 1 : 0;
    gather_kernel<<<gthBlocks, 256, 0, stream>>>(hb, rp_f, col_f, rp_b, col_b, sbufb, N);
    gemm_kernel<<<agBlocks, 512, 0, stream>>>(hb, sbufb,
                                              W_l+(size_t)i*DD*DD, W_r+(size_t)i*DD*DD,
                                              bias+(size_t)i*DD, batch, tb, gsum_i, gsq_i, N);
    norm2_kernel<<<nrmBlocks, 256, 0, stream>>>(tb, gsum_i, gsq_i, cnt, batch,
                                                gn_w+(size_t)i*DD, gn_b+(size_t)i*DD,
                                                gn_ms+(size_t)i*DD,
                                                hb, pout, (i>=2)?1:0, last, N);
  }
  finalize_kernel<<<16, 256, 0, stream>>>(pout, cnt, (float*)d_out);
}